// Round 14
// baseline (384.539 us; speedup 1.0000x reference)
//
#include <hip/hip_runtime.h>
#include <hip/hip_bf16.h>

typedef unsigned short ushort_t;
typedef __attribute__((ext_vector_type(8))) short bf16x8;
typedef __attribute__((ext_vector_type(4))) float f32x4;
typedef __attribute__((ext_vector_type(8))) unsigned short u16x8;
typedef __attribute__((ext_vector_type(4))) unsigned short u16x4;

#define NDIM 2048
#define BDIM 8

__device__ __forceinline__ float bf2f(unsigned short u) {
  union { unsigned int i; float f; } v; v.i = ((unsigned int)u) << 16; return v.f;
}
__device__ __forceinline__ unsigned short f2bf(float f) {
  union { float f; unsigned int i; } v; v.f = f;
  unsigned int x = v.i;
  x += 0x7fffu + ((x >> 16) & 1u);   // round to nearest even
  return (unsigned short)(x >> 16);
}

__device__ __forceinline__ void gload16(const void* g, void* l) {
  __builtin_amdgcn_global_load_lds(
      (const __attribute__((address_space(1))) void*)g,
      (__attribute__((address_space(3))) void*)l,
      16, 0, 0);
}

// ---------- prep: pack Wa to fragment layout + wbeff/wceff via atomics ----
// Subtile (mt,kt) blob: lane l holds Wa[mt*16+(l&15)][kt*32+(l>>4)*8 ..+8].
// Each wave covers 2 mt x 8 kt; weff partials reduced over fr then atomicAdd.
__global__ __launch_bounds__(256) void prep(const float* __restrict__ Wa,
                                            const float* __restrict__ Wb,
                                            const float* __restrict__ Wc,
                                            unsigned short* __restrict__ Apk,
                                            float* __restrict__ wbe,
                                            float* __restrict__ wce) {
  const int wv = threadIdx.x >> 6;          // 0..3
  const int l  = threadIdx.x & 63;
  const int fr = l & 15, fs = l >> 4;
  const int mt0 = blockIdx.y * 8 + wv * 2;
  const int o0  = mt0 * 16 + fr;
  const int o1  = o0 + 16;
  const float wb0 = Wb[o0], wb1 = Wb[o1];
  const float wc0 = Wc[o0], wc1 = Wc[o1];
  #pragma unroll
  for (int kt = 0; kt < 8; ++kt) {
    const int ktg = blockIdx.x * 8 + kt;
    const float* s0 = Wa + (size_t)o0 * NDIM + ktg * 32 + fs * 8;
    const float* s1 = Wa + (size_t)o1 * NDIM + ktg * 32 + fs * 8;
    f32x4 a0 = *(const f32x4*)&s0[0], a1 = *(const f32x4*)&s0[4];
    f32x4 b0 = *(const f32x4*)&s1[0], b1 = *(const f32x4*)&s1[4];
    u16x8 w0, w1;
    float p1[8], p2[8];
    #pragma unroll
    for (int j = 0; j < 4; ++j) {
      w0[j] = f2bf(a0[j]); w0[4 + j] = f2bf(a1[j]);
      w1[j] = f2bf(b0[j]); w1[4 + j] = f2bf(b1[j]);
      p1[j]     = wb0 * a0[j] + wb1 * b0[j];
      p1[4 + j] = wb0 * a1[j] + wb1 * b1[j];
      p2[j]     = wc0 * a0[j] + wc1 * b0[j];
      p2[4 + j] = wc0 * a1[j] + wc1 * b1[j];
    }
    *(u16x8*)&Apk[(size_t)(mt0 * 64 + ktg) * 512 + l * 8] = w0;
    *(u16x8*)&Apk[(size_t)((mt0 + 1) * 64 + ktg) * 512 + l * 8] = w1;
    #pragma unroll
    for (int j = 0; j < 8; ++j) {
      p1[j] += __shfl_xor(p1[j], 1); p1[j] += __shfl_xor(p1[j], 2);
      p1[j] += __shfl_xor(p1[j], 4); p1[j] += __shfl_xor(p1[j], 8);
      p2[j] += __shfl_xor(p2[j], 1); p2[j] += __shfl_xor(p2[j], 2);
      p2[j] += __shfl_xor(p2[j], 4); p2[j] += __shfl_xor(p2[j], 8);
    }
    if (fr == 0) {
      const int c = ktg * 32 + fs * 8;
      #pragma unroll
      for (int j = 0; j < 8; ++j) {
        atomicAdd(&wbe[c + j], p1[j]);
        atomicAdd(&wce[c + j], p2[j]);
      }
    }
  }
}

// ---------- x [b][c][n] f32 -> cur_T [b][n][c] bf16, fused t1/t2 partials ----
__global__ __launch_bounds__(256) void transpose_convert(
    const float* __restrict__ x, unsigned short* __restrict__ dst,
    const float* __restrict__ wbe, const float* __restrict__ wce,
    float* __restrict__ t1, float* __restrict__ t2) {
  __shared__ float tile[64][65];
  const int b  = blockIdx.z;
  const int n0 = blockIdx.x * 64;
  const int c0 = blockIdx.y * 64;
  const int tr = threadIdx.x >> 4;
  const int tc = threadIdx.x & 15;
  const float* src = x + ((size_t)b * NDIM + c0) * NDIM + n0;
  #pragma unroll
  for (int p = 0; p < 4; ++p) {
    int r = p * 16 + tr;
    f32x4 v = *(const f32x4*)&src[(size_t)r * NDIM + tc * 4];
    #pragma unroll
    for (int k = 0; k < 4; ++k) tile[r][tc * 4 + k] = v[k];
  }
  __syncthreads();
  float w1[4], w2[4];
  #pragma unroll
  for (int k = 0; k < 4; ++k) {
    w1[k] = wbe[c0 + tc * 4 + k];
    w2[k] = wce[c0 + tc * 4 + k];
  }
  unsigned short* d = dst + ((size_t)b * NDIM + n0) * NDIM + c0;
  #pragma unroll
  for (int p = 0; p < 4; ++p) {
    int r = p * 16 + tr;   // n-local
    u16x4 w;
    float a1 = 0.f, a2 = 0.f;
    #pragma unroll
    for (int k = 0; k < 4; ++k) {
      float v = tile[tc * 4 + k][r];
      w[k] = f2bf(v);
      a1 = fmaf(w1[k], v, a1);
      a2 = fmaf(w2[k], v, a2);
    }
    *(u16x4*)&d[(size_t)r * NDIM + tc * 4] = w;
    a1 += __shfl_xor(a1, 1); a1 += __shfl_xor(a1, 2);
    a1 += __shfl_xor(a1, 4); a1 += __shfl_xor(a1, 8);
    a2 += __shfl_xor(a2, 1); a2 += __shfl_xor(a2, 2);
    a2 += __shfl_xor(a2, 4); a2 += __shfl_xor(a2, 8);
    if (tc == 0) {
      atomicAdd(&t1[(size_t)b * NDIM + n0 + r], a1);
      atomicAdd(&t2[(size_t)b * NDIM + n0 + r], a2);
    }
  }
}

// ---------- S[o,n] = log sum_b exp(lrelu(t1[b,n]+t2[b,o]+bb+bc)) ----------
__global__ __launch_bounds__(256) void s_kernel(const float* __restrict__ t1,
                                                const float* __restrict__ t2,
                                                const float* __restrict__ bb,
                                                const float* __restrict__ bc,
                                                float* __restrict__ S) {
  int n = blockIdx.x * 256 + threadIdx.x;
  int o = blockIdx.y;
  const float bias2 = bb[0] + bc[0];
  float acc = 0.f;
  #pragma unroll
  for (int b = 0; b < BDIM; ++b) {
    float z = t1[b * NDIM + n] + t2[b * NDIM + o] + bias2;
    z = z >= 0.f ? z : 0.2f * z;
    acc += __expf(z);
  }
  S[(size_t)o * NDIM + n] = __logf(acc);
}

// ---------- fused GEMM + softmax-scale epilogue (+ next-step t partials) ----
// r13 structure; change: all 4 stB issue in phi0 (after issueA(Am1)), so the
// counted gates keep them in flight the WHOLE tile (~1250 cyc HBM cover vs
// 650 before). Outstanding-count trace (own-wave, steady state):
//   enter tile t: {Am0[t](8)}                       (stB[t] drained at t-1 end)
//   phi0: +Am1(8) +stB[t+1](4) = 20 -> vmcnt(12): drain Am0, keep Am1+stB
//   phi1: vmcnt(4): drain Am1, keep stB
//   phi3: +Am0[t+1](8) = 12
//   end:  vmcnt(8): drain stB[t+1] (B ready for t+1), keep Am0[t+1]
__global__ __launch_bounds__(512, 2) void gemm_fused(
    const unsigned short* __restrict__ Apk,  // packed A frags, 8 MB
    const unsigned short* __restrict__ Bt,   // cur_T bf16 [8][2048][2048]
    const float* __restrict__ t1, const float* __restrict__ t2,
    const float* __restrict__ bb, const float* __restrict__ bc,
    const float* __restrict__ S,  const float* __restrict__ bias,
    const float* __restrict__ wbe, const float* __restrict__ wce,
    float* __restrict__ t1o, float* __restrict__ t2o,
    unsigned short* __restrict__ outT,
    float* __restrict__ outF,
    int write_f32) {
  __shared__ __align__(16) unsigned short sbuf[2][16384];  // 2 x 32 KiB (B only)

  const int tid  = threadIdx.x;
  const int lane = tid & 63;
  const int w    = tid >> 6;
  const int wr   = w >> 2;             // 0..1
  const int wc   = w & 3;              // 0..3
  const int bn0  = blockIdx.x * 256;
  const int bm0  = blockIdx.y * 256;
  const int bz   = blockIdx.z;
  const unsigned short* Bb = Bt + (size_t)bz * NDIM * NDIM;

  f32x4 acc[8][4];
  #pragma unroll
  for (int m = 0; m < 8; ++m)
    #pragma unroll
    for (int n = 0; n < 4; ++n) acc[m][n] = (f32x4){0.f, 0.f, 0.f, 0.f};

  // ---- B staging decode (rows 128 B, slot-XOR swizzle, linear DMA dest) ----
  const int sst   = (lane & 7) ^ (lane >> 3);
  const int srowl = lane >> 3;
  const unsigned short* bG = Bb + (size_t)(bn0 + w * 32 + srowl) * NDIM + sst * 8;
  auto stB = [&](int T, int p, int d) {   // one gload = 8 rows
    gload16(bG + (size_t)p * 8 * NDIM + T * 64, &sbuf[d][(w * 32 + p * 8) * 64]);
  };

  // ---- B fragment decode (swizzled read) ----
  const int fr  = lane & 15;
  const int fs  = lane >> 4;
  const int sl0 = ((fs) ^ (fr & 7)) * 8;
  const int sl1 = ((4 + fs) ^ (fr & 7)) * 8;
  const int bRow = (wc * 64 + fr) * 64;

  // ---- A fragment global offsets: blob (mt*64 + kt)*1024 + lane*16 ----
  const unsigned int mtBase = (unsigned)((bm0 >> 4) + wr * 8);
  unsigned int aOff0[4], aOff1[4];
  #pragma unroll
  for (int m = 0; m < 4; ++m) {
    aOff0[m] = ((mtBase + m) * 64u) * 1024u + lane * 16u;
    aOff1[m] = ((mtBase + 4 + m) * 64u) * 1024u + lane * 16u;
  }

  bf16x8 Am0[4][2], Am1[4][2], bv[2][2];

  auto issueA = [&](bf16x8 (&dst)[4][2], const unsigned int (&off)[4]) {
    #pragma unroll
    for (int m = 0; m < 4; ++m) {
      asm volatile("global_load_dwordx4 %0, %1, %2"
                   : "=v"(dst[m][0]) : "v"(off[m]), "s"(Apk) : "memory");
      asm volatile("global_load_dwordx4 %0, %1, %2 offset:1024"
                   : "=v"(dst[m][1]) : "v"(off[m]), "s"(Apk) : "memory");
    }
  };
  auto rdB = [&](int nh, int d) {
    #pragma unroll
    for (int n = 0; n < 2; ++n) {
      const int base = d * 16384 + bRow + (nh * 2 + n) * 16 * 64;
      bv[n][0] = *(const bf16x8*)&sbuf[0][base + sl0];
      bv[n][1] = *(const bf16x8*)&sbuf[0][base + sl1];
    }
  };
  auto quad = [&](bf16x8 (&af)[4][2], int mo, int no) {
    __builtin_amdgcn_s_setprio(1);
    #pragma unroll
    for (int ks = 0; ks < 2; ++ks)
      #pragma unroll
      for (int m = 0; m < 4; ++m)
        #pragma unroll
        for (int n = 0; n < 2; ++n)
          acc[mo + m][no + n] = __builtin_amdgcn_mfma_f32_16x16x32_bf16(
              af[m][ks], bv[n][ks], acc[mo + m][no + n], 0, 0, 0);
    __builtin_amdgcn_s_setprio(0);
    __builtin_amdgcn_sched_barrier(0);
  };

  // ---- prologue: B[0]x4 then A-mh0[0]x8; vmcnt(8) drains B, keeps A ----
  stB(0, 0, 0); stB(0, 1, 0); stB(0, 2, 0); stB(0, 3, 0);
  issueA(Am0, aOff0);
  asm volatile("s_waitcnt vmcnt(8)" ::: "memory");
  __builtin_amdgcn_s_barrier();

  // ---- main loop: 32 K-tiles, 2-tile unrolled for compile-time buf parity --
  #pragma clang loop unroll(disable)
  for (int tt = 0; tt < 16; ++tt) {
    const int Tn0 = 2 * tt + 1;
    const int Tn1 = (tt == 15) ? 31 : 2 * tt + 2;

    #pragma unroll
    for (int half = 0; half < 2; ++half) {
      const int cur = half, nxt = half ^ 1;
      const int Tn = half ? Tn1 : Tn0;

      // phi0: issue A-mh1[t]; issue ALL B[t+1]; read B nh0;
      //       gate(Am0 landed) = vmcnt(12) (keeps Am1+stB); MFMA (mh0,nh0)
      issueA(Am1, aOff1);
      #pragma unroll
      for (int m = 0; m < 4; ++m) aOff1[m] += 2048u;
      stB(Tn, 0, nxt); stB(Tn, 1, nxt); stB(Tn, 2, nxt); stB(Tn, 3, nxt);
      rdB(0, cur);
      asm volatile("s_waitcnt vmcnt(12)" ::: "memory");
      __builtin_amdgcn_sched_barrier(0);             // rule #18
      quad(Am0, 0, 0);

      // phi1: gate(Am1 landed) = vmcnt(4) (keeps stB); MFMA (mh1,nh0)
      asm volatile("s_waitcnt vmcnt(4)" ::: "memory");
      __builtin_amdgcn_sched_barrier(0);
      quad(Am1, 4, 0);

      // phi2: read B nh1; MFMA (mh0,nh1)
      rdB(1, cur);
      #pragma unroll
      for (int m = 0; m < 4; ++m) aOff0[m] += 2048u;
      __builtin_amdgcn_sched_barrier(0);
      quad(Am0, 0, 2);

      // phi3: issue A-mh0[t+1]; MFMA (mh1,nh1)
      issueA(Am0, aOff0);
      __builtin_amdgcn_sched_barrier(0);
      quad(Am1, 4, 2);

      // tile end: vmcnt(8) drains stB[t+1] (full-tile cover), keeps Am0[t+1]
      asm volatile("s_waitcnt vmcnt(8)" ::: "memory");
      __builtin_amdgcn_s_barrier();
    }
  }

  asm volatile("s_waitcnt vmcnt(0)" ::: "memory");
  __syncthreads();

  // ---- epilogue ----
  float* sT1f = (float*)&sbuf[0][0];
  float* sT2f = sT1f + 256;
  if (tid < 256) sT1f[tid] = t1[bz * NDIM + bn0 + tid] + bb[0];
  else           sT2f[tid - 256] = t2[bz * NDIM + bm0 + (tid - 256)] + bc[0];
  __syncthreads();

  const int lr4 = fs * 4;
  if (write_f32) {
    #pragma unroll
    for (int m = 0; m < 8; ++m) {
      const int oo = wr * 128 + m * 16 + lr4;
      const int o  = bm0 + oo;
      #pragma unroll
      for (int n = 0; n < 4; ++n) {
        const int nn = wc * 64 + n * 16 + fr;
        const int ng = bn0 + nn;
        const float tz1  = sT1f[nn];
        const float bval = bias[ng];
        #pragma unroll
        for (int r = 0; r < 4; ++r) {
          float z = tz1 + sT2f[oo + r];
          z = z >= 0.f ? z : 0.2f * z;
          float coef = __expf(z - S[(size_t)(o + r) * NDIM + ng]);
          outF[(size_t)bz * NDIM * NDIM + (size_t)(o + r) * NDIM + ng] =
              fmaf(coef, acc[m][n][r], bval);
        }
      }
    }
  } else {
    float tp1[4] = {0.f, 0.f, 0.f, 0.f}, tp2[4] = {0.f, 0.f, 0.f, 0.f};
    #pragma unroll
    for (int m = 0; m < 8; ++m) {
      const int oo = wr * 128 + m * 16 + lr4;
      const int o  = bm0 + oo;
      float w1[4], w2[4];
      #pragma unroll
      for (int r = 0; r < 4; ++r) { w1[r] = wbe[o + r]; w2[r] = wce[o + r]; }
      #pragma unroll
      for (int n = 0; n < 4; ++n) {
        const int nn = wc * 64 + n * 16 + fr;
        const int ng = bn0 + nn;
        const float tz1  = sT1f[nn];
        const float bval = bias[ng];
        u16x4 wv;
        #pragma unroll
        for (int r = 0; r < 4; ++r) {
          float z = tz1 + sT2f[oo + r];
          z = z >= 0.f ? z : 0.2f * z;
          float coef = __expf(z - S[(size_t)(o + r) * NDIM + ng]);
          float val  = fmaf(coef, acc[m][n][r], bval);
          wv[r] = f2bf(val);
          tp1[n] = fmaf(w1[r], val, tp1[n]);
          tp2[n] = fmaf(w2[r], val, tp2[n]);
        }
        *(u16x4*)&outT[(size_t)bz * NDIM * NDIM + (size_t)ng * NDIM + o] = wv;
      }
    }
    #pragma unroll
    for (int n = 0; n < 4; ++n) {
      float a1 = tp1[n], a2 = tp2[n];
      a1 += __shfl_xor(a1, 16); a1 += __shfl_xor(a1, 32);
      a2 += __shfl_xor(a2, 16); a2 += __shfl_xor(a2, 32);
      if (fs == 0) {
        const int ng = bn0 + wc * 64 + n * 16 + fr;
        atomicAdd(&t1o[(size_t)bz * NDIM + ng], a1);
        atomicAdd(&t2o[(size_t)bz * NDIM + ng], a2);
      }
    }
  }
}

extern "C" void kernel_launch(void* const* d_in, const int* in_sizes, int n_in,
                              void* d_out, int out_size, void* d_ws, size_t ws_size,
                              hipStream_t stream) {
  const float* x    = (const float*)d_in[0];
  const float* Wa   = (const float*)d_in[1];
  const float* Wb   = (const float*)d_in[2];
  const float* bb   = (const float*)d_in[3];
  const float* Wc   = (const float*)d_in[4];
  const float* bc   = (const float*)d_in[5];
  const float* bias = (const float*)d_in[6];
  float* out = (float*)d_out;

  char* ws = (char*)d_ws;
  unsigned short* curA = (unsigned short*)ws; ws += (size_t)BDIM * NDIM * NDIM * 2;
  unsigned short* curB = (unsigned short*)ws; ws += (size_t)BDIM * NDIM * NDIM * 2;
  unsigned short* Apk  = (unsigned short*)ws; ws += (size_t)NDIM * NDIM * 2;
  float* t1a  = (float*)ws; ws += (size_t)BDIM * NDIM * 4;
  float* t2a  = (float*)ws; ws += (size_t)BDIM * NDIM * 4;
  float* t1b  = (float*)ws; ws += (size_t)BDIM * NDIM * 4;
  float* t2b  = (float*)ws; ws += (size_t)BDIM * NDIM * 4;
  float* wbe  = (float*)ws; ws += NDIM * 4;
  float* wce  = (float*)ws; ws += NDIM * 4;
  float* S    = (float*)ws; ws += (size_t)NDIM * NDIM * 4;

  // t1a..t2b, wbe, wce are contiguous: one memset zeroes all atomics targets
  hipMemsetAsync(t1a, 0, ((size_t)4 * BDIM * NDIM + 2 * NDIM) * 4, stream);

  prep<<<dim3(8, 16), 256, 0, stream>>>(Wa, Wb, Wc, Apk, wbe, wce);
  transpose_convert<<<dim3(32, 32, BDIM), 256, 0, stream>>>(x, curA, wbe, wce, t1a, t2a);

  // step 0: curA -> curB (bf16 transposed), accumulate t1b/t2b
  s_kernel<<<dim3(NDIM / 256, NDIM), 256, 0, stream>>>(t1a, t2a, bb, bc, S);
  gemm_fused<<<dim3(8, 8, BDIM), 512, 0, stream>>>(
      Apk, curA, t1a, t2a, bb, bc, S, bias, wbe, wce, t1b, t2b, curB, out, 0);

  // step 1: curB -> out (f32)
  s_kernel<<<dim3(NDIM / 256, NDIM), 256, 0, stream>>>(t1b, t2b, bb, bc, S);
  gemm_fused<<<dim3(8, 8, BDIM), 512, 0, stream>>>(
      Apk, curB, t1b, t2b, bb, bc, S, bias, wbe, wce, t1a, t2a, curB, out, 1);
}

// Round 15
// 364.947 us; speedup vs baseline: 1.0537x; 1.0537x over previous
//
#include <hip/hip_runtime.h>
#include <hip/hip_bf16.h>

typedef unsigned short ushort_t;
typedef __attribute__((ext_vector_type(8))) short bf16x8;
typedef __attribute__((ext_vector_type(4))) float f32x4;
typedef __attribute__((ext_vector_type(8))) unsigned short u16x8;
typedef __attribute__((ext_vector_type(4))) unsigned short u16x4;

#define NDIM 2048
#define BDIM 8

__device__ __forceinline__ float bf2f(unsigned short u) {
  union { unsigned int i; float f; } v; v.i = ((unsigned int)u) << 16; return v.f;
}
__device__ __forceinline__ unsigned short f2bf(float f) {
  union { float f; unsigned int i; } v; v.f = f;
  unsigned int x = v.i;
  x += 0x7fffu + ((x >> 16) & 1u);   // round to nearest even
  return (unsigned short)(x >> 16);
}

__device__ __forceinline__ void gload16(const void* g, void* l) {
  __builtin_amdgcn_global_load_lds(
      (const __attribute__((address_space(1))) void*)g,
      (__attribute__((address_space(3))) void*)l,
      16, 0, 0);
}

// ---------- Wa f32 -> fragment-packed bf16 A ----------
__global__ __launch_bounds__(256) void pack_a(const float* __restrict__ Wa,
                                              unsigned short* __restrict__ Apk) {
  const int sub = blockIdx.x * 4 + (threadIdx.x >> 6);   // 0..8191
  const int l   = threadIdx.x & 63;
  const int mt  = sub >> 6, kt = sub & 63;
  const int fr  = l & 15, fs = l >> 4;
  const float* src = Wa + (size_t)(mt * 16 + fr) * NDIM + kt * 32 + fs * 8;
  f32x4 v0 = *(const f32x4*)&src[0];
  f32x4 v1 = *(const f32x4*)&src[4];
  u16x8 w;
  #pragma unroll
  for (int k = 0; k < 4; ++k) { w[k] = f2bf(v0[k]); w[4 + k] = f2bf(v1[k]); }
  *(u16x8*)&Apk[(size_t)sub * 512 + l * 8] = w;
}

// ---------- x [b][c][n] f32 -> cur_T [b][n][c] bf16, fused t1/t2 partials ----
__global__ __launch_bounds__(256) void transpose_convert(
    const float* __restrict__ x, unsigned short* __restrict__ dst,
    const float* __restrict__ wbe, const float* __restrict__ wce,
    float* __restrict__ t1, float* __restrict__ t2) {
  __shared__ float tile[64][65];
  const int b  = blockIdx.z;
  const int n0 = blockIdx.x * 64;
  const int c0 = blockIdx.y * 64;
  const int tr = threadIdx.x >> 4;
  const int tc = threadIdx.x & 15;
  const float* src = x + ((size_t)b * NDIM + c0) * NDIM + n0;
  #pragma unroll
  for (int p = 0; p < 4; ++p) {
    int r = p * 16 + tr;
    f32x4 v = *(const f32x4*)&src[(size_t)r * NDIM + tc * 4];
    #pragma unroll
    for (int k = 0; k < 4; ++k) tile[r][tc * 4 + k] = v[k];
  }
  __syncthreads();
  float w1[4], w2[4];
  #pragma unroll
  for (int k = 0; k < 4; ++k) {
    w1[k] = wbe[c0 + tc * 4 + k];
    w2[k] = wce[c0 + tc * 4 + k];
  }
  unsigned short* d = dst + ((size_t)b * NDIM + n0) * NDIM + c0;
  #pragma unroll
  for (int p = 0; p < 4; ++p) {
    int r = p * 16 + tr;   // n-local
    u16x4 w;
    float a1 = 0.f, a2 = 0.f;
    #pragma unroll
    for (int k = 0; k < 4; ++k) {
      float v = tile[tc * 4 + k][r];
      w[k] = f2bf(v);
      a1 = fmaf(w1[k], v, a1);
      a2 = fmaf(w2[k], v, a2);
    }
    *(u16x4*)&d[(size_t)r * NDIM + tc * 4] = w;
    a1 += __shfl_xor(a1, 1); a1 += __shfl_xor(a1, 2);
    a1 += __shfl_xor(a1, 4); a1 += __shfl_xor(a1, 8);
    a2 += __shfl_xor(a2, 1); a2 += __shfl_xor(a2, 2);
    a2 += __shfl_xor(a2, 4); a2 += __shfl_xor(a2, 8);
    if (tc == 0) {
      atomicAdd(&t1[(size_t)b * NDIM + n0 + r], a1);
      atomicAdd(&t2[(size_t)b * NDIM + n0 + r], a2);
    }
  }
}

// ---------- wbeff = Wa^T Wb, wceff = Wa^T Wc ----------
__global__ __launch_bounds__(256) void weff1(const float* __restrict__ Wa,
                                             const float* __restrict__ Wb,
                                             const float* __restrict__ Wc,
                                             float* __restrict__ part) {
  int c  = blockIdx.x * 256 + threadIdx.x;
  int o0 = blockIdx.y * 128;
  float ab = 0.f, ac = 0.f;
  for (int o = o0; o < o0 + 128; ++o) {
    float w = Wa[(size_t)o * NDIM + c];
    ab = fmaf(Wb[o], w, ab);
    ac = fmaf(Wc[o], w, ac);
  }
  part[(size_t)(blockIdx.y * 2 + 0) * NDIM + c] = ab;
  part[(size_t)(blockIdx.y * 2 + 1) * NDIM + c] = ac;
}
__global__ __launch_bounds__(256) void weff2(const float* __restrict__ part,
                                             float* __restrict__ wbe, float* __restrict__ wce) {
  int c = blockIdx.x * 256 + threadIdx.x;
  float ab = 0.f, ac = 0.f;
  #pragma unroll
  for (int i = 0; i < 16; ++i) {
    ab += part[(size_t)(i * 2 + 0) * NDIM + c];
    ac += part[(size_t)(i * 2 + 1) * NDIM + c];
  }
  wbe[c] = ab; wce[c] = ac;
}

// ---------- S[o,n] = log sum_b exp(lrelu(t1[b,n]+t2[b,o]+bb+bc)) ----------
__global__ __launch_bounds__(256) void s_kernel(const float* __restrict__ t1,
                                                const float* __restrict__ t2,
                                                const float* __restrict__ bb,
                                                const float* __restrict__ bc,
                                                float* __restrict__ S) {
  int n = blockIdx.x * 256 + threadIdx.x;
  int o = blockIdx.y;
  const float bias2 = bb[0] + bc[0];
  float acc = 0.f;
  #pragma unroll
  for (int b = 0; b < BDIM; ++b) {
    float z = t1[b * NDIM + n] + t2[b * NDIM + o] + bias2;
    z = z >= 0.f ? z : 0.2f * z;
    acc += __expf(z);
  }
  S[(size_t)o * NDIM + n] = __logf(acc);
}

// ---------- fused GEMM + softmax-scale epilogue (+ next-step t partials) ----
// Best-measured configuration (r13 bench, 361 us total): 256x256 tile, BK=64,
// 8 waves (2M x 4N); A direct global->VGPR from fragment-packed layout; B via
// global_load_lds 2x32KB dbuf; one barrier per K-tile; counted vmcnt gates;
// quad() iterates ks outermost (dep distance 8, bit-identical sum order).
__global__ __launch_bounds__(512, 2) void gemm_fused(
    const unsigned short* __restrict__ Apk,  // packed A frags, 8 MB
    const unsigned short* __restrict__ Bt,   // cur_T bf16 [8][2048][2048]
    const float* __restrict__ t1, const float* __restrict__ t2,
    const float* __restrict__ bb, const float* __restrict__ bc,
    const float* __restrict__ S,  const float* __restrict__ bias,
    const float* __restrict__ wbe, const float* __restrict__ wce,
    float* __restrict__ t1o, float* __restrict__ t2o,
    unsigned short* __restrict__ outT,
    float* __restrict__ outF,
    int write_f32) {
  __shared__ __align__(16) unsigned short sbuf[2][16384];  // 2 x 32 KiB (B only)

  const int tid  = threadIdx.x;
  const int lane = tid & 63;
  const int w    = tid >> 6;
  const int wr   = w >> 2;             // 0..1
  const int wc   = w & 3;              // 0..3
  const int bn0  = blockIdx.x * 256;
  const int bm0  = blockIdx.y * 256;
  const int bz   = blockIdx.z;
  const unsigned short* Bb = Bt + (size_t)bz * NDIM * NDIM;

  f32x4 acc[8][4];
  #pragma unroll
  for (int m = 0; m < 8; ++m)
    #pragma unroll
    for (int n = 0; n < 4; ++n) acc[m][n] = (f32x4){0.f, 0.f, 0.f, 0.f};

  // ---- B staging decode (rows 128 B, slot-XOR swizzle, linear DMA dest) ----
  const int sst   = (lane & 7) ^ (lane >> 3);
  const int srowl = lane >> 3;
  const unsigned short* bG = Bb + (size_t)(bn0 + w * 32 + srowl) * NDIM + sst * 8;
  auto stB = [&](int T, int p, int d) {   // one gload = 8 rows
    gload16(bG + (size_t)p * 8 * NDIM + T * 64, &sbuf[d][(w * 32 + p * 8) * 64]);
  };

  // ---- B fragment decode (swizzled read) ----
  const int fr  = lane & 15;
  const int fs  = lane >> 4;
  const int sl0 = ((fs) ^ (fr & 7)) * 8;
  const int sl1 = ((4 + fs) ^ (fr & 7)) * 8;
  const int bRow = (wc * 64 + fr) * 64;

  // ---- A fragment global offsets: blob (mt*64 + kt)*1024 + lane*16 ----
  const unsigned int mtBase = (unsigned)((bm0 >> 4) + wr * 8);
  unsigned int aOff0[4], aOff1[4];
  #pragma unroll
  for (int m = 0; m < 4; ++m) {
    aOff0[m] = ((mtBase + m) * 64u) * 1024u + lane * 16u;
    aOff1[m] = ((mtBase + 4 + m) * 64u) * 1024u + lane * 16u;
  }

  bf16x8 Am0[4][2], Am1[4][2], bv[2][2];

  auto issueA = [&](bf16x8 (&dst)[4][2], const unsigned int (&off)[4]) {
    #pragma unroll
    for (int m = 0; m < 4; ++m) {
      asm volatile("global_load_dwordx4 %0, %1, %2"
                   : "=v"(dst[m][0]) : "v"(off[m]), "s"(Apk) : "memory");
      asm volatile("global_load_dwordx4 %0, %1, %2 offset:1024"
                   : "=v"(dst[m][1]) : "v"(off[m]), "s"(Apk) : "memory");
    }
  };
  auto rdB = [&](int nh, int d) {
    #pragma unroll
    for (int n = 0; n < 2; ++n) {
      const int base = d * 16384 + bRow + (nh * 2 + n) * 16 * 64;
      bv[n][0] = *(const bf16x8*)&sbuf[0][base + sl0];
      bv[n][1] = *(const bf16x8*)&sbuf[0][base + sl1];
    }
  };
  // ks OUTERMOST: 8 independent MFMAs per ks pass; each acc written twice,
  // 8 apart. Per-element order still ks0 -> ks1 (bit-identical result).
  auto quad = [&](bf16x8 (&af)[4][2], int mo, int no) {
    __builtin_amdgcn_s_setprio(1);
    #pragma unroll
    for (int ks = 0; ks < 2; ++ks)
      #pragma unroll
      for (int m = 0; m < 4; ++m)
        #pragma unroll
        for (int n = 0; n < 2; ++n)
          acc[mo + m][no + n] = __builtin_amdgcn_mfma_f32_16x16x32_bf16(
              af[m][ks], bv[n][ks], acc[mo + m][no + n], 0, 0, 0);
    __builtin_amdgcn_s_setprio(0);
    __builtin_amdgcn_sched_barrier(0);
  };

  // ---- prologue: B[0] -> buf0; A-mh0[0]; B landed, A in flight ----
  stB(0, 0, 0); stB(0, 1, 0); stB(0, 2, 0); stB(0, 3, 0);
  issueA(Am0, aOff0);
  asm volatile("s_waitcnt vmcnt(8)" ::: "memory");
  __builtin_amdgcn_s_barrier();

  // ---- main loop: 32 K-tiles, 2-tile unrolled for compile-time buf parity --
  #pragma clang loop unroll(disable)
  for (int tt = 0; tt < 16; ++tt) {
    const int Tn0 = 2 * tt + 1;
    const int Tn1 = (tt == 15) ? 31 : 2 * tt + 2;

    #pragma unroll
    for (int half = 0; half < 2; ++half) {
      const int cur = half, nxt = half ^ 1;
      const int Tn = half ? Tn1 : Tn0;

      // phi0: issue A-mh1[t]; read B nh0; gate(A-mh0 landed); MFMA (mh0,nh0)
      issueA(Am1, aOff1);
      #pragma unroll
      for (int m = 0; m < 4; ++m) aOff1[m] += 2048u;
      rdB(0, cur);
      asm volatile("s_waitcnt vmcnt(8)" ::: "memory");
      __builtin_amdgcn_sched_barrier(0);             // rule #18
      quad(Am0, 0, 0);

      // phi1: issue B[t+1] pair-a; gate(A-mh1 landed); MFMA (mh1,nh0)
      stB(Tn, 0, nxt); stB(Tn, 1, nxt);
      asm volatile("s_waitcnt vmcnt(2)" ::: "memory");
      __builtin_amdgcn_sched_barrier(0);
      quad(Am1, 4, 0);

      // phi2: issue B[t+1] pair-b; read B nh1; MFMA (mh0,nh1)
      stB(Tn, 2, nxt); stB(Tn, 3, nxt);
      rdB(1, cur);
      #pragma unroll
      for (int m = 0; m < 4; ++m) aOff0[m] += 2048u;
      __builtin_amdgcn_sched_barrier(0);
      quad(Am0, 0, 2);

      // phi3: issue A-mh0[t+1]; MFMA (mh1,nh1)
      issueA(Am0, aOff0);
      __builtin_amdgcn_sched_barrier(0);
      quad(Am1, 4, 2);

      // tile end: both B pairs landed; barrier
      asm volatile("s_waitcnt vmcnt(8)" ::: "memory");
      __builtin_amdgcn_s_barrier();
    }
  }

  asm volatile("s_waitcnt vmcnt(0)" ::: "memory");
  __syncthreads();

  // ---- epilogue ----
  float* sT1f = (float*)&sbuf[0][0];
  float* sT2f = sT1f + 256;
  if (tid < 256) sT1f[tid] = t1[bz * NDIM + bn0 + tid] + bb[0];
  else           sT2f[tid - 256] = t2[bz * NDIM + bm0 + (tid - 256)] + bc[0];
  __syncthreads();

  const int lr4 = fs * 4;
  if (write_f32) {
    #pragma unroll
    for (int m = 0; m < 8; ++m) {
      const int oo = wr * 128 + m * 16 + lr4;
      const int o  = bm0 + oo;
      #pragma unroll
      for (int n = 0; n < 4; ++n) {
        const int nn = wc * 64 + n * 16 + fr;
        const int ng = bn0 + nn;
        const float tz1  = sT1f[nn];
        const float bval = bias[ng];
        #pragma unroll
        for (int r = 0; r < 4; ++r) {
          float z = tz1 + sT2f[oo + r];
          z = z >= 0.f ? z : 0.2f * z;
          float coef = __expf(z - S[(size_t)(o + r) * NDIM + ng]);
          outF[(size_t)bz * NDIM * NDIM + (size_t)(o + r) * NDIM + ng] =
              fmaf(coef, acc[m][n][r], bval);
        }
      }
    }
  } else {
    float tp1[4] = {0.f, 0.f, 0.f, 0.f}, tp2[4] = {0.f, 0.f, 0.f, 0.f};
    #pragma unroll
    for (int m = 0; m < 8; ++m) {
      const int oo = wr * 128 + m * 16 + lr4;
      const int o  = bm0 + oo;
      float w1[4], w2[4];
      #pragma unroll
      for (int r = 0; r < 4; ++r) { w1[r] = wbe[o + r]; w2[r] = wce[o + r]; }
      #pragma unroll
      for (int n = 0; n < 4; ++n) {
        const int nn = wc * 64 + n * 16 + fr;
        const int ng = bn0 + nn;
        const float tz1  = sT1f[nn];
        const float bval = bias[ng];
        u16x4 wv;
        #pragma unroll
        for (int r = 0; r < 4; ++r) {
          float z = tz1 + sT2f[oo + r];
          z = z >= 0.f ? z : 0.2f * z;
          float coef = __expf(z - S[(size_t)(o + r) * NDIM + ng]);
          float val  = fmaf(coef, acc[m][n][r], bval);
          wv[r] = f2bf(val);
          tp1[n] = fmaf(w1[r], val, tp1[n]);
          tp2[n] = fmaf(w2[r], val, tp2[n]);
        }
        *(u16x4*)&outT[(size_t)bz * NDIM * NDIM + (size_t)ng * NDIM + o] = wv;
      }
    }
    #pragma unroll
    for (int n = 0; n < 4; ++n) {
      float a1 = tp1[n], a2 = tp2[n];
      a1 += __shfl_xor(a1, 16); a1 += __shfl_xor(a1, 32);
      a2 += __shfl_xor(a2, 16); a2 += __shfl_xor(a2, 32);
      if (fs == 0) {
        const int ng = bn0 + wc * 64 + n * 16 + fr;
        atomicAdd(&t1o[(size_t)bz * NDIM + ng], a1);
        atomicAdd(&t2o[(size_t)bz * NDIM + ng], a2);
      }
    }
  }
}

extern "C" void kernel_launch(void* const* d_in, const int* in_sizes, int n_in,
                              void* d_out, int out_size, void* d_ws, size_t ws_size,
                              hipStream_t stream) {
  const float* x    = (const float*)d_in[0];
  const float* Wa   = (const float*)d_in[1];
  const float* Wb   = (const float*)d_in[2];
  const float* bb   = (const float*)d_in[3];
  const float* Wc   = (const float*)d_in[4];
  const float* bc   = (const float*)d_in[5];
  const float* bias = (const float*)d_in[6];
  float* out = (float*)d_out;

  char* ws = (char*)d_ws;
  unsigned short* curA = (unsigned short*)ws; ws += (size_t)BDIM * NDIM * NDIM * 2;
  unsigned short* curB = (unsigned short*)ws; ws += (size_t)BDIM * NDIM * NDIM * 2;
  unsigned short* Apk  = (unsigned short*)ws; ws += (size_t)NDIM * NDIM * 2;
  float* t1a  = (float*)ws; ws += (size_t)BDIM * NDIM * 4;
  float* t2a  = (float*)ws; ws += (size_t)BDIM * NDIM * 4;
  float* t1b  = (float*)ws; ws += (size_t)BDIM * NDIM * 4;
  float* t2b  = (float*)ws; ws += (size_t)BDIM * NDIM * 4;
  float* wbe  = (float*)ws; ws += NDIM * 4;
  float* wce  = (float*)ws; ws += NDIM * 4;
  float* part = (float*)ws; ws += (size_t)32 * NDIM * 4;
  float* S    = (float*)ws; ws += (size_t)NDIM * NDIM * 4;

  // t1a..t2b are contiguous: one memset
  hipMemsetAsync(t1a, 0, (size_t)4 * BDIM * NDIM * 4, stream);

  pack_a<<<2048, 256, 0, stream>>>(Wa, Apk);
  weff1<<<dim3(8, 16), 256, 0, stream>>>(Wa, Wb, Wc, part);
  weff2<<<8, 256, 0, stream>>>(part, wbe, wce);
  transpose_convert<<<dim3(32, 32, BDIM), 256, 0, stream>>>(x, curA, wbe, wce, t1a, t2a);

  // step 0: curA -> curB (bf16 transposed), accumulate t1b/t2b
  s_kernel<<<dim3(NDIM / 256, NDIM), 256, 0, stream>>>(t1a, t2a, bb, bc, S);
  gemm_fused<<<dim3(8, 8, BDIM), 512, 0, stream>>>(
      Apk, curA, t1a, t2a, bb, bc, S, bias, wbe, wce, t1b, t2b, curB, out, 0);

  // step 1: curB -> out (f32)
  s_kernel<<<dim3(NDIM / 256, NDIM), 256, 0, stream>>>(t1b, t2b, bb, bc, S);
  gemm_fused<<<dim3(8, 8, BDIM), 512, 0, stream>>>(
      Apk, curB, t1b, t2b, bb, bc, S, bias, wbe, wce, t1a, t2a, curB, out, 1);
}